// Round 5
// baseline (1856.727 us; speedup 1.0000x reference)
//
#include <hip/hip_runtime.h>
#include <hip/hip_bf16.h>

// BasicBlock sparse conv v12: compacted output-stationary conv.
// Evidence base: (R1+R3 A/B) exec-masked == unconditional gathers -> vmem cost
// is per-INSTRUCTION; only fewer gather instructions help. Dense structure:
// 27 planes x 256 rows at 29% density = 5.4M row-visits/conv (~60M lane-addrs,
// ~100us TA-bound). v12: per-(block,plane) compacted entry lists
// (entry = in_idx | lrow<<18, padded to 16-entry MFMA tiles with zero-row
// sentinel), LDS f32 accumulator [256][68] via ds_add_f32 (atomic,
// fire-and-forget), B weights in 32 VGPRs per wave-owned plane (no B-LDS, no
// main-loop barriers; center plane tile-strided across waves). Row-visits
// 5.4M -> 1.93M; lane-addrs ~35M -> predicted conv ~60-80us, total ~230-260.
// nbrT/fill/scatter removed; lists built from in/out_maps (atomic append;
// f32 add-order nondeterminism ~1e-6, tolerance has ~30x headroom).
// Cross-session lesson (v8 vs v11 identical code, conv "95" vs "124"):
// trust bench totals, not cross-session rocprof durations.

#define N_VOX 200000
#define NB 782               // output blocks of 256 rows (NB*256 = 200192)
#define EPS_BN 1e-5f
#define SENT N_VOX           // sentinel entry: in_idx=N_VOX (zero row), lrow=0

typedef __attribute__((ext_vector_type(8))) short bf16x8;   // 8 bf16 = 4 VGPRs
typedef __attribute__((ext_vector_type(4))) float f32x4;

// ---------------- prep kernels ----------------

__global__ void zero_cnt_kernel(int* __restrict__ cntT, float* __restrict__ sums) {
    int i = blockIdx.x * 256 + threadIdx.x;
    if (i < NB * 27) cntT[i] = 0;
    if (i < 256) sums[i] = 0.f;
}

// center plane (p=13): identity list, entry count = valid rows of block
__global__ void ident_kernel(int* __restrict__ lists, int* __restrict__ cntT) {
    int b = blockIdx.x, r = threadIdx.x;
    int row = b * 256 + r;
    int s = b * 27 + 13;
    lists[s * 256 + r] = (row < N_VOX) ? (row | (r << 18)) : SENT;
    if (r == 0) {
        int c = N_VOX - b * 256; if (c > 256) c = 256;
        cntT[s] = c;
    }
}

// sparse planes: atomic append of (in_idx | lrow<<18) per (block, plane)
__global__ void build_kernel(const int* __restrict__ out_maps,
                             const int* __restrict__ in_maps,
                             int* __restrict__ lists, int* __restrict__ cntT) {
    int idx = blockIdx.x * 256 + threadIdx.x;     // < 26*65536
    int o = out_maps[idx];
    if (o < N_VOX) {
        int k = idx >> 16;                        // offset 0..25
        int p = k + (k >= 13);                    // weight plane (skip center)
        int s = (o >> 8) * 27 + p;
        int pos = atomicAdd(&cntT[s], 1);         // pos < 256 (o unique per k)
        lists[s * 256 + pos] = in_maps[idx] | ((o & 255) << 18);
    }
}

// pad each list to a multiple of 16 entries; convert cnt -> tile count
__global__ void pad_kernel(int* __restrict__ lists, int* __restrict__ cntT) {
    int s = blockIdx.x * 256 + threadIdx.x;
    if (s >= NB * 27) return;
    int c = cntT[s];
    int nt = (c + 15) >> 4;
    for (int e = c; e < nt * 16; ++e) lists[s * 256 + e] = SENT;
    cntT[s] = nt;
}

__global__ void cast_x_kernel(const float* __restrict__ x,
                              __hip_bfloat16* __restrict__ xb) {
    long i = ((long)blockIdx.x * 256 + threadIdx.x) * 4;
    if (i >= (long)(N_VOX + 1) * 64) return;
    __hip_bfloat16 t[4];
    if (i < (long)N_VOX * 64) {
        float4 v = *(const float4*)(x + i);
        t[0] = __float2bfloat16(v.x); t[1] = __float2bfloat16(v.y);
        t[2] = __float2bfloat16(v.z); t[3] = __float2bfloat16(v.w);
    } else {
        t[0] = t[1] = t[2] = t[3] = __float2bfloat16(0.0f);  // zero row N
    }
    *(ushort4*)(xb + i) = *(ushort4*)t;
}

// W4: weights swizzled to MFMA B-fragment lane order.
// W4[((k*8 + g)*64 + lane)*8 + j],  g = ct*2+half, c = half*32+quad*8+j, d = ct*16+m.
__global__ void cast_w_kernel(const float* __restrict__ W1, const float* __restrict__ W2,
                              __hip_bfloat16* __restrict__ W1S, __hip_bfloat16* __restrict__ W2S) {
    int idx = blockIdx.x * 256 + threadIdx.x;
    if (idx >= 27 * 4096) return;
    int j    = idx & 7;
    int lane = (idx >> 3) & 63;
    int g    = idx >> 9;           // k*8 + ct*2 + half
    int half = g & 1, ct = (g >> 1) & 3, k = g >> 3;
    int m = lane & 15, quad = lane >> 4;
    int c = half * 32 + quad * 8 + j;
    int d = ct * 16 + m;
    int src = k * 4096 + c * 64 + d;
    W1S[idx] = __float2bfloat16(W1[src]);
    W2S[idx] = __float2bfloat16(W2[src]);
}

// ---------------- conv kernel ----------------
// block = 256 output rows, 4 waves. facc[256][68] f32 in LDS (ds_add_f32).
// Wave-owned sparse planes (B in regs, no barriers); center tile-strided.

__global__ __launch_bounds__(256, 2) void conv_kernel(
    const __hip_bfloat16* __restrict__ xb,   // [(N+1)*64]
    const __hip_bfloat16* __restrict__ W4,   // [27*4096] swizzled
    const int* __restrict__ lists,           // [NB*27*256] packed entries
    const int* __restrict__ cntT,            // [NB*27] tile counts
    __hip_bfloat16* __restrict__ h,          // [N*64] bf16
    float* __restrict__ sums)                // [128]: sum[64], sumsq[64]
{
    const int tid  = threadIdx.x;
    const int lane = tid & 63;
    const int wave = tid >> 6;
    const int m    = lane & 15;
    const int quad = lane >> 4;
    const int b    = blockIdx.x;

    __shared__ __align__(16) float smem[256 * 68 + 128];   // 70144 B
    float* facc  = smem;                 // [256][68] (68: 16B-aligned b128 + bank spread)
    float* bnsum = smem + 256 * 68;      // [64]
    float* bnsq  = bnsum + 64;           // [64]

    for (int i = tid; i < 256 * 68 + 128; i += 256) smem[i] = 0.f;
    __syncthreads();

    // Process tiles [t0, nt) step stp of plane p. A lane (quad,m): row = entry[m],
    // k = hf*32 + quad*8 + j. C: row-in-tile = quad*4+r, channel = ct*16+m.
#define PROC_PLANE(p, t0, stp)                                                       \
    {                                                                                \
        bf16x8 B[8];                                                                 \
        const __hip_bfloat16* wsrc = W4 + (p) * 4096 + lane * 8;                     \
        _Pragma("unroll")                                                            \
        for (int f = 0; f < 8; ++f) B[f] = *(const bf16x8*)(wsrc + f * 512);         \
        const int s = b * 27 + (p);                                                  \
        const int nt = cntT[s];                                                      \
        const int* eb = lists + s * 256;                                             \
        int t = (t0);                                                                \
        if (t < nt) {                                                                \
            int ecur = eb[t * 16 + m];                                               \
            const __hip_bfloat16* rr = xb + (long)(ecur & 0x3FFFF) * 64 + quad * 8;  \
            bf16x8 a0 = *(const bf16x8*)rr;                                          \
            bf16x8 a1 = *(const bf16x8*)(rr + 32);                                   \
            for (; t < nt; t += (stp)) {                                             \
                int enx = ecur; bf16x8 n0 = a0, n1 = a1;                             \
                if (t + (stp) < nt) {     /* uniform branch: prefetch next tile */   \
                    enx = eb[(t + (stp)) * 16 + m];                                  \
                    const __hip_bfloat16* rn = xb + (long)(enx & 0x3FFFF) * 64 + quad * 8; \
                    n0 = *(const bf16x8*)rn;                                         \
                    n1 = *(const bf16x8*)(rn + 32);                                  \
                }                                                                    \
                f32x4 c0 = {0.f,0.f,0.f,0.f}, c1 = c0, c2 = c0, c3 = c0;             \
                c0 = __builtin_amdgcn_mfma_f32_16x16x32_bf16(a0, B[0], c0, 0,0,0);   \
                c0 = __builtin_amdgcn_mfma_f32_16x16x32_bf16(a1, B[1], c0, 0,0,0);   \
                c1 = __builtin_amdgcn_mfma_f32_16x16x32_bf16(a0, B[2], c1, 0,0,0);   \
                c1 = __builtin_amdgcn_mfma_f32_16x16x32_bf16(a1, B[3], c1, 0,0,0);   \
                c2 = __builtin_amdgcn_mfma_f32_16x16x32_bf16(a0, B[4], c2, 0,0,0);   \
                c2 = __builtin_amdgcn_mfma_f32_16x16x32_bf16(a1, B[5], c2, 0,0,0);   \
                c3 = __builtin_amdgcn_mfma_f32_16x16x32_bf16(a0, B[6], c3, 0,0,0);   \
                c3 = __builtin_amdgcn_mfma_f32_16x16x32_bf16(a1, B[7], c3, 0,0,0);   \
                _Pragma("unroll")                                                    \
                for (int r = 0; r < 4; ++r) {                                        \
                    int er = __shfl(ecur, quad * 4 + r);                             \
                    int lr = er >> 18;                                               \
                    float* dst = facc + lr * 68 + m;                                 \
                    atomicAdd(dst,      c0[r]);    /* ds_add_f32, no-return */       \
                    atomicAdd(dst + 16, c1[r]);                                      \
                    atomicAdd(dst + 32, c2[r]);                                      \
                    atomicAdd(dst + 48, c3[r]);                                      \
                }                                                                    \
                ecur = enx; a0 = n0; a1 = n1;                                        \
            }                                                                        \
        }                                                                            \
    }

    // center plane: 16 tiles, strided across all 4 waves (load balance)
    PROC_PLANE(13, wave, 4)
    // sparse planes: whole-plane ownership, k = wave, wave+4, ...
    for (int k = wave; k < 26; k += 4) {
        int p = k + (k >= 13);
        PROC_PLANE(p, 0, 1)
    }
#undef PROC_PLANE

    __syncthreads();   // all ds_adds complete (lgkmcnt drained by barrier)

    // ---- epilogue: BN partials + h store ----
    // thread covers rows wave*64+quad*16+i (i=0..15), channels m*4..m*4+3
    float s0=0,s1=0,s2=0,s3=0, q0=0,q1=0,q2=0,q3=0;
    const int lrow0 = wave * 64 + quad * 16;
    const int rb = b * 256 + lrow0;
#pragma unroll
    for (int i = 0; i < 16; ++i) {
        int grow = rb + i;
        if (grow < N_VOX) {
            f32x4 v = *(const f32x4*)(facc + (lrow0 + i) * 68 + m * 4);
            s0 += v.x; s1 += v.y; s2 += v.z; s3 += v.w;
            q0 += v.x*v.x; q1 += v.y*v.y; q2 += v.z*v.z; q3 += v.w*v.w;
            __hip_bfloat16 t4[4];
            t4[0] = __float2bfloat16(v.x); t4[1] = __float2bfloat16(v.y);
            t4[2] = __float2bfloat16(v.z); t4[3] = __float2bfloat16(v.w);
            *(ushort4*)(h + (long)grow * 64 + m * 4) = *(ushort4*)t4;
        }
    }
    const int c0i = m * 4;
    atomicAdd(&bnsum[c0i + 0], s0); atomicAdd(&bnsum[c0i + 1], s1);
    atomicAdd(&bnsum[c0i + 2], s2); atomicAdd(&bnsum[c0i + 3], s3);
    atomicAdd(&bnsq [c0i + 0], q0); atomicAdd(&bnsq [c0i + 1], q1);
    atomicAdd(&bnsq [c0i + 2], q2); atomicAdd(&bnsq [c0i + 3], q3);
    __syncthreads();
    if (tid < 64) {
        atomicAdd(&sums[tid], bnsum[tid]);
        atomicAdd(&sums[64 + tid], bnsq[tid]);
    }
}

// ---------------- BN1 + relu + cast to bf16 (conv2 input) ----------------

__global__ void bnrelu_kernel(const __hip_bfloat16* __restrict__ h, const float* __restrict__ sums,
                              const float* __restrict__ gamma, const float* __restrict__ beta,
                              __hip_bfloat16* __restrict__ hb) {
    long i = ((long)blockIdx.x * 256 + threadIdx.x) * 4;
    if (i >= (long)(N_VOX + 1) * 64) return;
    __hip_bfloat16 t[4];
    if (i < (long)N_VOX * 64) {
        int c0 = (int)(i & 63);
        ushort4 raw = *(const ushort4*)(h + i);
        __hip_bfloat16 hv[4];
        *(ushort4*)hv = raw;
#pragma unroll
        for (int j = 0; j < 4; ++j) {
            int c = c0 + j;
            float mu  = sums[c] * (1.0f / N_VOX);
            float var = sums[64 + c] * (1.0f / N_VOX) - mu * mu;
            float rs  = rsqrtf(var + EPS_BN);
            float val = gamma[c] * (__bfloat162float(hv[j]) - mu) * rs + beta[c];
            t[j] = __float2bfloat16(fmaxf(val, 0.0f));
        }
    } else {
        t[0] = t[1] = t[2] = t[3] = __float2bfloat16(0.0f);   // zero row N
    }
    *(ushort4*)(hb + i) = *(ushort4*)t;
}

// ---------------- BN2 + residual + relu -> d_out ----------------

__global__ void final_kernel(const __hip_bfloat16* __restrict__ h, const float* __restrict__ x,
                             const float* __restrict__ sums, const float* __restrict__ gamma,
                             const float* __restrict__ beta, float* __restrict__ out) {
    long i = ((long)blockIdx.x * 256 + threadIdx.x) * 4;
    if (i >= (long)N_VOX * 64) return;
    int c0 = (int)(i & 63);
    ushort4 raw = *(const ushort4*)(h + i);
    __hip_bfloat16 hv[4];
    *(ushort4*)hv = raw;
    float4 xr = *(const float4*)(x + i);
    float xx[4] = {xr.x, xr.y, xr.z, xr.w};
    float oo[4];
#pragma unroll
    for (int j = 0; j < 4; ++j) {
        int c = c0 + j;
        float mu  = sums[c] * (1.0f / N_VOX);
        float var = sums[64 + c] * (1.0f / N_VOX) - mu * mu;
        float rs  = rsqrtf(var + EPS_BN);
        float val = gamma[c] * (__bfloat162float(hv[j]) - mu) * rs + beta[c] + xx[j];
        oo[j] = fmaxf(val, 0.0f);
    }
    float4 ov = {oo[0], oo[1], oo[2], oo[3]};
    *(float4*)(out + i) = ov;
}

// ---------------- launcher ----------------

extern "C" void kernel_launch(void* const* d_in, const int* in_sizes, int n_in,
                              void* d_out, int out_size, void* d_ws, size_t ws_size,
                              hipStream_t stream) {
    const float* x      = (const float*)d_in[0];
    const float* W1     = (const float*)d_in[1];
    const float* gamma1 = (const float*)d_in[2];
    const float* beta1  = (const float*)d_in[3];
    const float* W2     = (const float*)d_in[4];
    const float* gamma2 = (const float*)d_in[5];
    const float* beta2  = (const float*)d_in[6];
    const int* in_maps  = (const int*)d_in[7];
    const int* out_maps = (const int*)d_in[8];
    float* out = (float*)d_out;

    char* ws = (char*)d_ws;
    size_t off = 0;
    auto alloc = [&](size_t bytes) -> void* {
        void* p = ws + off;
        off = (off + bytes + 255) & ~(size_t)255;
        return p;
    };
    int* lists          = (int*)alloc((size_t)NB * 27 * 256 * 4);               // 21.6 MB
    int* cntT           = (int*)alloc((size_t)NB * 27 * 4);
    __hip_bfloat16* xb  = (__hip_bfloat16*)alloc((size_t)(N_VOX + 1) * 64 * 2); // 25.6 MB (reused as h1b)
    __hip_bfloat16* W1S = (__hip_bfloat16*)alloc((size_t)27 * 4096 * 2);
    __hip_bfloat16* W2S = (__hip_bfloat16*)alloc((size_t)27 * 4096 * 2);
    __hip_bfloat16* h   = (__hip_bfloat16*)alloc((size_t)N_VOX * 64 * 2);       // 25.6 MB
    float* sums         = (float*)alloc(256 * 4);
    __hip_bfloat16* h1b = xb;   // xb dead after conv1; reuse for BN1(relu) output

    const long elem_x = (long)(N_VOX + 1) * 64;
    const int grid_sp = (NB * 27 + 255) / 256;   // 83

    zero_cnt_kernel<<<grid_sp, 256, 0, stream>>>(cntT, sums);
    ident_kernel   <<<NB, 256, 0, stream>>>(lists, cntT);
    build_kernel   <<<26 * 65536 / 256, 256, 0, stream>>>(out_maps, in_maps, lists, cntT);
    pad_kernel     <<<grid_sp, 256, 0, stream>>>(lists, cntT);
    cast_x_kernel  <<<(int)((elem_x / 4 + 255) / 256), 256, 0, stream>>>(x, xb);
    cast_w_kernel  <<<(27 * 4096 + 255) / 256, 256, 0, stream>>>(W1, W2, W1S, W2S);

    conv_kernel    <<<NB, 256, 0, stream>>>(xb, W1S, lists, cntT, h, sums);
    bnrelu_kernel  <<<(int)((elem_x / 4 + 255) / 256), 256, 0, stream>>>(h, sums, gamma1, beta1, h1b);

    conv_kernel    <<<NB, 256, 0, stream>>>(h1b, W2S, lists, cntT, h, sums + 128);
    final_kernel   <<<(int)(((long)N_VOX * 64 / 4 + 255) / 256), 256, 0, stream>>>(h, x, sums + 128, gamma2, beta2, out);
}